// Round 3
// baseline (2022.633 us; speedup 1.0000x reference)
//
#include <hip/hip_runtime.h>
#include <hip/hip_bf16.h>
#include <cstdint>
#include <cstddef>

// Problem sizes
#define VOCABN   50257
#define EMBN     300
#define HIDN     1024
#define BATCHN   4096
#define KGATE    1344     // 320 (padded EMB) + 1024 (HID)
#define GATEN    4096     // 4 gates * 1024
#define NPADV    50304    // 393 * 128

using u16 = unsigned short;

typedef short bf16x8 __attribute__((ext_vector_type(8)));   // 8 bf16 in 4 VGPRs
typedef float f32x4  __attribute__((ext_vector_type(4)));

__device__ __forceinline__ u16 f2bf(float f) {
    unsigned u = __builtin_bit_cast(unsigned, f);
    u += 0x7fffu + ((u >> 16) & 1u);
    return (u16)(u >> 16);
}

__device__ __forceinline__ float sigf(float x) { return 1.f / (1.f + expf(-x)); }

__device__ __forceinline__ void gld_lds16(void* lds, const void* g) {
    __builtin_amdgcn_global_load_lds(
        (const __attribute__((address_space(1))) void*)g,
        (__attribute__((address_space(3))) void*)lds,
        16, 0, 0);
}

// ---------------------------------------------------------------------------
// Kernel 1: A1[m][k] bf16 = [ emb_table[X_idx[m]][0..299] | 0 pad | H[m][0..1023] ]
// ---------------------------------------------------------------------------
__global__ __launch_bounds__(256) void build_A1(
    const int* __restrict__ X_idx, const float* __restrict__ H,
    const float* __restrict__ emb, u16* __restrict__ A1)
{
    int m = blockIdx.x;
    const float* erow = emb + (size_t)X_idx[m] * EMBN;
    const float* hrow = H + (size_t)m * HIDN;
    u16* arow = A1 + (size_t)m * KGATE;
    for (int c = threadIdx.x; c < KGATE; c += 256) {
        float v;
        if (c < EMBN)      v = erow[c];
        else if (c < 320)  v = 0.f;
        else               v = hrow[c - 320];
        arow[c] = f2bf(v);
    }
}

// ---------------------------------------------------------------------------
// Kernel 2: Bt1[n][k] bf16, n = gate*1024 + j:
//   k<300 -> Wx_g[k][j]; 300<=k<320 -> 0; k>=320 -> Wh_g[k-320][j]
// Tiled 32x32 transpose (coalesced both sides).
// ---------------------------------------------------------------------------
__global__ __launch_bounds__(256) void tr_gates(
    const float* wxf, const float* wxi, const float* wxg, const float* wxo,
    const float* whf, const float* whi, const float* whg, const float* who,
    u16* __restrict__ Bt1)
{
    __shared__ float t[32][33];
    const float* wx[4] = {wxf, wxi, wxg, wxo};
    const float* wh[4] = {whf, whi, whg, who};
    int tx = threadIdx.x, ty = threadIdx.y;
    int n0 = blockIdx.x * 32, k0 = blockIdx.y * 32;
    int g = n0 >> 10, j0 = n0 & 1023;
    const float* WX = wx[g];
    const float* WH = wh[g];
    int j = j0 + tx;
    for (int i = ty; i < 32; i += 8) {
        int k = k0 + i;
        float v = 0.f;
        if (k < EMBN)      v = WX[(size_t)k * HIDN + j];
        else if (k >= 320) v = WH[(size_t)(k - 320) * HIDN + j];
        t[i][tx] = v;
    }
    __syncthreads();
    for (int i = ty; i < 32; i += 8) {
        int n = n0 + i, k = k0 + tx;
        Bt1[(size_t)n * KGATE + k] = f2bf(t[tx][i]);
    }
}

// ---------------------------------------------------------------------------
// Kernel 3: Bt2[n][k] bf16 = W_logits[k][n] (n < VOCAB), zero-pad to NPADV rows
// ---------------------------------------------------------------------------
__global__ __launch_bounds__(256) void tr_logits(
    const float* __restrict__ W, u16* __restrict__ Bt2)
{
    __shared__ float t[32][33];
    int tx = threadIdx.x, ty = threadIdx.y;
    int n0 = blockIdx.x * 32, k0 = blockIdx.y * 32;
    int n = n0 + tx;
    for (int i = ty; i < 32; i += 8) {
        int k = k0 + i;
        t[i][tx] = (n < VOCABN) ? W[(size_t)k * VOCABN + n] : 0.f;
    }
    __syncthreads();
    for (int i = ty; i < 32; i += 8) {
        int nn = n0 + i, k = k0 + tx;
        Bt2[(size_t)nn * HIDN + k] = f2bf(t[tx][i]);
    }
}

// ---------------------------------------------------------------------------
// Kernel 4: bf16 GEMM, A[M][lda] x Bt[N][ldb]^T -> C[M][ldc] fp32.
// 128x128 block tile, BK=32, 4 waves (each 64x64 = 4x4 of 16x16x32 MFMA).
// LDS kblk-major layout: chunk c in [0,512): [kblk=c>>7][row=c&127][8 bf16]
//   -> fragment ds_read_b128 conflict-free (16B stride across lanes).
// global_load_lds width 16 staging, single buffer, 2 barriers per K-step.
// ---------------------------------------------------------------------------
template<bool BIAS, bool NCHK>
__global__ __launch_bounds__(256) void gemm_bt(
    const u16* __restrict__ A, const u16* __restrict__ Bt,
    float* __restrict__ Cout, const float* __restrict__ bias,
    int K, int lda, int ldb, int ldc, int Nreal)
{
    __shared__ u16 sA[4 * 128 * 8];
    __shared__ u16 sB[4 * 128 * 8];

    const int tid  = threadIdx.x;
    const int wid  = tid >> 6, lane = tid & 63;
    const int mt   = blockIdx.x, nt = blockIdx.y;
    const int wr   = wid >> 1, wc = wid & 1;
    const int lrow = lane & 15, kq = lane >> 4;

    f32x4 acc[4][4];
#pragma unroll
    for (int m = 0; m < 4; ++m)
#pragma unroll
        for (int n = 0; n < 4; ++n)
            acc[m][n] = f32x4{0.f, 0.f, 0.f, 0.f};

    // staging decode: pass0 chunk=tid (kblk 0/1), pass1 chunk=tid+256 (kblk 2/3)
    const int srow = tid & 127, skb = tid >> 7;
    const u16* gA = A + (size_t)(mt * 128 + srow) * lda + skb * 8;
    const u16* gB = Bt + (size_t)(nt * 128 + srow) * ldb + skb * 8;
    u16* sA0 = sA + wid * 512;          // pass0 wave base (chunks wid*64..)
    u16* sA1 = sA + 2048 + wid * 512;   // pass1 wave base
    u16* sB0 = sB + wid * 512;
    u16* sB1 = sB + 2048 + wid * 512;

    const u16* pa = sA + (size_t)(kq * 128 + wr * 64 + lrow) * 8;
    const u16* pb = sB + (size_t)(kq * 128 + wc * 64 + lrow) * 8;

    const int KT = K >> 5;
    for (int kt = 0; kt < KT; ++kt) {
        const int k0 = kt * 32;
        gld_lds16(sA0, gA + k0);
        gld_lds16(sA1, gA + k0 + 16);
        gld_lds16(sB0, gB + k0);
        gld_lds16(sB1, gB + k0 + 16);
        __syncthreads();   // compiler emits s_waitcnt vmcnt(0) before barrier

        bf16x8 aF[4], bF[4];
#pragma unroll
        for (int m = 0; m < 4; ++m) aF[m] = *(const bf16x8*)(pa + m * 128);
#pragma unroll
        for (int n = 0; n < 4; ++n) bF[n] = *(const bf16x8*)(pb + n * 128);
#pragma unroll
        for (int m = 0; m < 4; ++m)
#pragma unroll
            for (int n = 0; n < 4; ++n)
                acc[m][n] = __builtin_amdgcn_mfma_f32_16x16x32_bf16(
                    aF[m], bF[n], acc[m][n], 0, 0, 0);
        __syncthreads();   // all reads done before next-stage overwrite
    }

    // epilogue: C row = mt*128 + wr*64 + m*16 + kq*4 + r ; col = nt*128 + wc*64 + n*16 + lrow
    const int rowb = mt * 128 + wr * 64 + kq * 4;
    const int colb = nt * 128 + wc * 64 + lrow;
#pragma unroll
    for (int n = 0; n < 4; ++n) {
        const int col = colb + n * 16;
        const bool ok = (!NCHK) || (col < Nreal);
        const float bv = (BIAS && ok) ? bias[col] : 0.f;
        if (ok) {
#pragma unroll
            for (int m = 0; m < 4; ++m) {
#pragma unroll
                for (int r = 0; r < 4; ++r) {
                    Cout[(size_t)(rowb + m * 16 + r) * ldc + col] = acc[m][n][r] + bv;
                }
            }
        }
    }
}

// ---------------------------------------------------------------------------
// Kernel 5: LSTM cell elementwise. pre[m][4096] = [f|i|g|o] preacts (no bias).
// Adds biases, activations, C_new = f*C + i*g, H_new = o*tanh(C_new) -> bf16 A2.
// ---------------------------------------------------------------------------
__global__ __launch_bounds__(256) void lstm_cell(
    const float* __restrict__ pre, const float* __restrict__ Cst,
    const float* bfx, const float* bfh, const float* bix, const float* bih,
    const float* bgx, const float* bgh, const float* box_, const float* boh,
    u16* __restrict__ A2)
{
    int m = blockIdx.x, t = threadIdx.x;
    const float4* P = (const float4*)(pre + (size_t)m * GATEN);
    float4 pf = P[t], pi = P[256 + t], pg = P[512 + t], po = P[768 + t];
    float4 cc = ((const float4*)(Cst + (size_t)m * HIDN))[t];
    float4 vfx = ((const float4*)bfx)[t], vfh = ((const float4*)bfh)[t];
    float4 vix = ((const float4*)bix)[t], vih = ((const float4*)bih)[t];
    float4 vgx = ((const float4*)bgx)[t], vgh = ((const float4*)bgh)[t];
    float4 vox = ((const float4*)box_)[t], voh = ((const float4*)boh)[t];
    ushort4 out;
#define LSTM_COMP(w)                                              \
    {                                                             \
        float f_ = sigf(pf.w + vfx.w + vfh.w);                    \
        float i_ = sigf(pi.w + vix.w + vih.w);                    \
        float g_ = tanhf(pg.w + vgx.w + vgh.w);                   \
        float o_ = sigf(po.w + vox.w + voh.w);                    \
        float c_ = f_ * cc.w + i_ * g_;                           \
        out.w = f2bf(o_ * tanhf(c_));                             \
    }
    LSTM_COMP(x) LSTM_COMP(y) LSTM_COMP(z) LSTM_COMP(w)
#undef LSTM_COMP
    ((ushort4*)(A2 + (size_t)m * HIDN))[t] = out;
}

// ---------------------------------------------------------------------------
// Workspace layout (peak 111.4 MB; Bt2 overlays A1/Bt1/pre after GEMM1):
//   A2  @ 0          :  8,388,608   (4096*1024*2)   live: lstm_cell..GEMM2
//   A1  @ 8388608    : 11,010,048   (4096*1344*2)   live: build_A1..GEMM1
//   Bt1 @ 19398656   : 11,010,048   (4096*1344*2)   live: tr_gates..GEMM1
//   pre @ 30408704   : 67,108,864   (4096*4096*4)   live: GEMM1..lstm_cell
//   Bt2 @ 8388608    : 103,022,592  (50304*1024*2)  live: tr_logits..GEMM2
// ---------------------------------------------------------------------------
extern "C" void kernel_launch(void* const* d_in, const int* in_sizes, int n_in,
                              void* d_out, int out_size, void* d_ws, size_t ws_size,
                              hipStream_t stream)
{
    const int*   X_idx = (const int*)d_in[0];
    const float* H     = (const float*)d_in[1];
    const float* C     = (const float*)d_in[2];
    const float* emb   = (const float*)d_in[3];
    const float* Wx[4] = {(const float*)d_in[4], (const float*)d_in[8],
                          (const float*)d_in[12], (const float*)d_in[16]};
    const float* bx[4] = {(const float*)d_in[5], (const float*)d_in[9],
                          (const float*)d_in[13], (const float*)d_in[17]};
    const float* Wh[4] = {(const float*)d_in[6], (const float*)d_in[10],
                          (const float*)d_in[14], (const float*)d_in[18]};
    const float* bh[4] = {(const float*)d_in[7], (const float*)d_in[11],
                          (const float*)d_in[15], (const float*)d_in[19]};
    const float* Wlog  = (const float*)d_in[20];
    const float* blog  = (const float*)d_in[21];
    float* out = (float*)d_out;

    char* ws = (char*)d_ws;
    u16*   A2  = (u16*)(ws);
    u16*   A1  = (u16*)(ws + 8388608);
    u16*   Bt1 = (u16*)(ws + 19398656);
    float* pre = (float*)(ws + 30408704);
    u16*   Bt2 = (u16*)(ws + 8388608);   // overlays A1/Bt1/pre (dead by then)

    // 1) A1 = [emb_gather | H] bf16
    build_A1<<<dim3(BATCHN), dim3(256), 0, stream>>>(X_idx, H, emb, A1);
    // 2) Bt1 = gate weights transposed+packed bf16
    tr_gates<<<dim3(GATEN / 32, KGATE / 32), dim3(32, 8), 0, stream>>>(
        Wx[0], Wx[1], Wx[2], Wx[3], Wh[0], Wh[1], Wh[2], Wh[3], Bt1);
    // 3) GEMM1: pre = A1 @ Bt1^T   [4096 x 4096 x 1344]
    gemm_bt<false, false><<<dim3(BATCHN / 128, GATEN / 128), dim3(256), 0, stream>>>(
        A1, Bt1, pre, nullptr, KGATE, KGATE, KGATE, GATEN, GATEN);
    // 4) LSTM cell elementwise -> A2 (H_new bf16)
    lstm_cell<<<dim3(BATCHN), dim3(256), 0, stream>>>(
        pre, C, bx[0], bh[0], bx[1], bh[1], bx[2], bh[2], bx[3], bh[3], A2);
    // 5) Bt2 = W_logits^T bf16, padded to NPADV rows (A1/Bt1/pre now dead)
    tr_logits<<<dim3(NPADV / 32, HIDN / 32), dim3(32, 8), 0, stream>>>(Wlog, Bt2);
    // 6) GEMM2: out = A2 @ Bt2^T + b_logits  [4096 x 50304(pad) x 1024]
    //    grid.x = M tiles (fastest) so consecutive blocks share the B-panel (L2 reuse)
    gemm_bt<true, true><<<dim3(BATCHN / 128, NPADV / 128), dim3(256), 0, stream>>>(
        A2, Bt2, out, blog, HIDN, HIDN, HIDN, VOCABN, VOCABN);
}